// Round 8
// baseline (1454.124 us; speedup 1.0000x reference)
//
#include <hip/hip_runtime.h>
#include <stdint.h>

// ---------------- problem constants ----------------
constexpr int BZ   = 64;          // batch
constexpr int SEQ  = 577;         // sequence length
constexpr int DM   = 768;         // model dim
constexpr int NH   = 12;          // heads
constexpr int HD   = 64;          // head dim
constexpr int FFD  = 3072;        // mlp hidden
constexpr int ROWS = BZ * SEQ;    // 36928 token rows
constexpr int BHN  = BZ * NH;     // 768 (b,h) pairs
constexpr int VTS  = 640;         // padded t-stride for V^T

typedef __attribute__((ext_vector_type(8))) short bf16x8;  // 8 bf16 = 4 VGPRs
typedef __attribute__((ext_vector_type(4))) float f32x4;   // MFMA C/D frag

static __device__ __forceinline__ unsigned short f2bf(float f) {
  union { float f; uint32_t u; } v; v.f = f;
  uint32_t r = (v.u + 0x7FFFu + ((v.u >> 16) & 1u)) >> 16;  // RNE
  return (unsigned short)r;
}

static __device__ __forceinline__ f32x4 mfma16(bf16x8 a, bf16x8 b, f32x4 c) {
  return __builtin_amdgcn_mfma_f32_16x16x32_bf16(a, b, c, 0, 0, 0);
}

// async global->LDS, 16B per lane; LDS dest = wave-uniform base + lane*16.
static __device__ __forceinline__ void gload_lds16(const unsigned short* g, unsigned short* l) {
  __builtin_amdgcn_global_load_lds((const __attribute__((address_space(1))) unsigned int*)g,
                                   (__attribute__((address_space(3))) unsigned int*)l, 16, 0, 0);
}

// ---------------- weight prep: fp32 -> bf16, transposed to [N][K] ----------------
__global__ __launch_bounds__(256) void prep_qkv(const float* __restrict__ Wq,
                                                const float* __restrict__ Wk,
                                                const float* __restrict__ Wv,
                                                unsigned short* __restrict__ dst) {
  int tid = blockIdx.x * 256 + threadIdx.x;           // 2304*768 total, exact grid
  int n = tid / DM, k = tid - n * DM;
  int seg = n / DM;                                    // 0..2
  int within = n - seg * DM;
  int h = within >> 6, e = within & 63;
  const float* W = (seg == 0) ? Wq : (seg == 1) ? Wk : Wv;
  dst[tid] = f2bf(W[((size_t)h * DM + k) * HD + e]);
}

__global__ __launch_bounds__(256) void prep_t(const float* __restrict__ src,
                                              unsigned short* __restrict__ dst,
                                              int N, int K) {
  int tid = blockIdx.x * 256 + threadIdx.x;
  if (tid >= N * K) return;
  int n = tid / K, k = tid - n * K;
  dst[tid] = f2bf(src[(size_t)k * N + n]);
}

// ---------------- layernorm: fp32 [rows,768] -> bf16 [rows,768] ----------------
__global__ __launch_bounds__(256) void ln_bf16(const float* __restrict__ X,
                                               const float* __restrict__ g,
                                               const float* __restrict__ b,
                                               unsigned short* __restrict__ out) {
  int row  = blockIdx.x * 4 + (threadIdx.x >> 6);
  int lane = threadIdx.x & 63;
  const float* x = X + (size_t)row * DM;
  float4 v[3];
  float s = 0.f, s2 = 0.f;
#pragma unroll
  for (int i = 0; i < 3; i++) {
    v[i] = *(const float4*)(x + i * 256 + lane * 4);
    s  += v[i].x + v[i].y + v[i].z + v[i].w;
    s2 += v[i].x * v[i].x + v[i].y * v[i].y + v[i].z * v[i].z + v[i].w * v[i].w;
  }
#pragma unroll
  for (int o = 1; o < 64; o <<= 1) { s += __shfl_xor(s, o); s2 += __shfl_xor(s2, o); }
  float mu  = s * (1.f / DM);
  float var = s2 * (1.f / DM) - mu * mu;
  float inv = rsqrtf(var + 1e-6f);
#pragma unroll
  for (int i = 0; i < 3; i++) {
    int c = i * 256 + lane * 4;
    float4 gg = *(const float4*)(g + c);
    float4 bb = *(const float4*)(b + c);
    ushort4 o4;
    o4.x = f2bf((v[i].x - mu) * inv * gg.x + bb.x);
    o4.y = f2bf((v[i].y - mu) * inv * gg.y + bb.y);
    o4.z = f2bf((v[i].z - mu) * inv * gg.z + bb.z);
    o4.w = f2bf((v[i].w - mu) * inv * gg.w + bb.w);
    *(ushort4*)(out + (size_t)row * DM + c) = o4;
  }
}

// ---------------- tiled bf16 MFMA GEMM: C = A[M,K] * Bt[N,K]^T ----------------
// 128x128 tile, BK=64, 256 threads, 32KB LDS — proven structure.
// XOR chunk swizzle keeps global_load_lds linear dest; ds_read phases conflict-free.
// Staging pointers hoisted (loop-carried += 64). EPI0: div-free batch split.
// EPI2: bf16 output gathered through LDS (sAB dead after K-loop) and stored as
// full 64B lines — kills TCC write-allocate FETCH (~227MB at W1).
template <int EPI>
__global__ __launch_bounds__(256) void gemm_bt(
    const unsigned short* __restrict__ A, const unsigned short* __restrict__ Bt,
    int M, int N, int K, int nbn,
    const float* __restrict__ bias0, const float* __restrict__ bias1,
    const float* __restrict__ bias2, const float* __restrict__ xres,
    float* __restrict__ outf,
    unsigned short* __restrict__ ob0, unsigned short* __restrict__ ob1,
    unsigned short* __restrict__ ob2) {
  __shared__ __align__(16) unsigned short sAB[2][128 * 64];   // sA=sAB[0], sB=sAB[1]
  const int tid  = threadIdx.x;
  const int wave = tid >> 6;
  const int lane = tid & 63;
  const int l15 = lane & 15, quad = lane >> 4;

  // bijective XCD-chunk remap: blocks with L%8==x (same XCD) get consecutive g
  const int nb = gridDim.x;
  const int L = blockIdx.x;
  const int per = nb >> 3, rem = nb & 7;
  const int x8 = L & 7, i8 = L >> 3;
  const int g = x8 * per + (x8 < rem ? x8 : rem) + i8;
  const int mt = g / nbn, nt = g - mt * nbn;
  const int m0 = mt * 128, n0 = nt * 128;
  const int wm = (wave >> 1) * 64, wn = (wave & 1) * 64;

  // ---- staging pointers hoisted: computed once, advanced by 64 per K-tile ----
  const unsigned short* srcA[4];
  const unsigned short* srcB[4];
  int sOff[4];
#pragma unroll
  for (int j = 0; j < 4; j++) {
    int c = tid + j * 256;                 // 0..1023
    int row = c >> 3, col = c & 7;
    int kc = col ^ (row & 7);              // pre-swizzled global chunk
    int ra = m0 + row; if (ra >= M) ra = M - 1;           // clamp tail rows
    srcA[j] = A + (size_t)ra * K + kc * 8;
    srcB[j] = Bt + (size_t)(n0 + row) * K + kc * 8;
    sOff[j] = c * 8;
  }

  f32x4 acc[4][4] = {};
  const int nkt = K >> 6;
  for (int kt = 0; kt < nkt; ++kt) {
    // stage 16KB A + 16KB B; addresses are loop-carried pointers (no recompute)
#pragma unroll
    for (int j = 0; j < 4; j++) {
      gload_lds16(srcA[j], &sAB[0][sOff[j]]);
      gload_lds16(srcB[j], &sAB[1][sOff[j]]);
    }
#pragma unroll
    for (int j = 0; j < 4; j++) { srcA[j] += 64; srcB[j] += 64; }
    __syncthreads();
#pragma unroll
    for (int h = 0; h < 2; h++) {
      bf16x8 aF[4], bF[4];
      const int swz = ((h << 2) | quad) ^ (l15 & 7);   // row ≡ l15 mod 8 for all frags
#pragma unroll
      for (int mi = 0; mi < 4; mi++) aF[mi] = *(const bf16x8*)(&sAB[0][0] + (wm + mi * 16 + l15) * 64 + swz * 8);
#pragma unroll
      for (int ni = 0; ni < 4; ni++) bF[ni] = *(const bf16x8*)(&sAB[1][0] + (wn + ni * 16 + l15) * 64 + swz * 8);
#pragma unroll
      for (int mi = 0; mi < 4; mi++)
#pragma unroll
        for (int ni = 0; ni < 4; ni++) acc[mi][ni] = mfma16(aF[mi], bF[ni], acc[mi][ni]);
    }
    __syncthreads();
  }

  // ---------------- epilogue ----------------
  const int bb0  = m0 / SEQ;            // 128-tile spans at most one SEQ boundary
  const int bb0s = bb0 * SEQ;

  if constexpr (EPI == 2) {
    if (m0 + 128 <= M) {
      // full-tile path: gelu -> LDS (xor-swizzled) -> full-line coalesced stores
      unsigned short* sT = &sAB[0][0];                 // 128*128 shorts = 32KB
#pragma unroll
      for (int mi = 0; mi < 4; mi++) {
#pragma unroll
        for (int r = 0; r < 4; r++) {
          int row = wm + mi * 16 + quad * 4 + r;       // local m 0..127
#pragma unroll
          for (int ni = 0; ni < 4; ni++) {
            int col = wn + ni * 16 + l15;              // local n 0..127
            float xv = acc[mi][ni][r] + bias0[n0 + col];
            float x2 = xv * xv;
            float tp = fmaf(x2, 0.0713548163f, 1.5957691216f);
            float m2u = xv * tp;                                   // 2u
            float e  = exp2f(m2u * -1.4426950408889634f);          // exp(-2u)
            float gel = xv * __builtin_amdgcn_rcpf(1.f + e);
            sT[row * 128 + (col ^ ((row & 7) << 4))] = f2bf(gel);
          }
        }
      }
      __syncthreads();
      // 2048 chunk-stores of 8 bf16: row = cid>>4 (0..127), c16 = cid&15 (0..15).
      // XOR hits bits 4-6 of the element index -> 8-elem chunks stay 16B-aligned.
#pragma unroll
      for (int k = 0; k < 8; k++) {
        int cid = tid + k * 256;                       // 0..2047
        int row = cid >> 4, c16 = cid & 15;
        bf16x8 v = *(const bf16x8*)(sT + row * 128 + ((c16 * 8) ^ ((row & 7) << 4)));
        *(bf16x8*)(ob0 + (size_t)(m0 + row) * FFD + n0 + c16 * 8) = v;
      }
    } else {
      // tail m-tile: per-element path
#pragma unroll
      for (int mi = 0; mi < 4; mi++) {
#pragma unroll
        for (int r = 0; r < 4; r++) {
          int mg = m0 + wm + mi * 16 + quad * 4 + r;
          if (mg >= M) continue;
          size_t base = (size_t)mg * FFD;
#pragma unroll
          for (int ni = 0; ni < 4; ni++) {
            int col = n0 + wn + ni * 16 + l15;
            float xv = acc[mi][ni][r] + bias0[col];
            float x2 = xv * xv;
            float tp = fmaf(x2, 0.0713548163f, 1.5957691216f);
            float m2u = xv * tp;
            float e  = exp2f(m2u * -1.4426950408889634f);
            float gel = xv * __builtin_amdgcn_rcpf(1.f + e);
            ob0[base + col] = f2bf(gel);
          }
        }
      }
    }
  } else {
#pragma unroll
    for (int mi = 0; mi < 4; mi++) {
#pragma unroll
      for (int r = 0; r < 4; r++) {
        int mg = m0 + wm + mi * 16 + quad * 4 + r;
        if (mg >= M) continue;
        if constexpr (EPI == 0) {
          int ss = mg - bb0s, bb = bb0;
          if (ss >= SEQ) { ss -= SEQ; bb++; }
          int seg = n0 / DM;
          int within0 = n0 - seg * DM + wn;
#pragma unroll
          for (int ni = 0; ni < 4; ni++) {
            int wcol = within0 + ni * 16 + l15;
            int h = wcol >> 6, e = wcol & 63;
            float val = acc[mi][ni][r];
            if (seg == 0) {
              float qv = (val + bias0[wcol]) * 0.125f;   // fold 1/sqrt(64)
              ob0[((size_t)(bb * NH + h) * SEQ + ss) * HD + e] = f2bf(qv);
            } else if (seg == 1) {
              float kv = val + bias1[wcol];
              ob1[((size_t)(bb * NH + h) * SEQ + ss) * HD + e] = f2bf(kv);
            } else {
              float vv = val + bias2[wcol];
              ob2[((size_t)(bb * NH + h) * HD + e) * VTS + ss] = f2bf(vv);  // V transposed
            }
          }
        } else if constexpr (EPI == 1) {
          size_t base = (size_t)mg * DM;
#pragma unroll
          for (int ni = 0; ni < 4; ni++) {
            int col = n0 + wn + ni * 16 + l15;
            outf[base + col] = xres[base + col] + acc[mi][ni][r] + bias0[col];
          }
        } else {  // EPI == 3
          size_t base = (size_t)mg * DM;
#pragma unroll
          for (int ni = 0; ni < 4; ni++) {
            int col = n0 + wn + ni * 16 + l15;
            outf[base + col] += acc[mi][ni][r] + bias0[col];
          }
        }
      }
    }
  }
}

// ---------------- flash attention: 256 thr, 128 q-rows/block, 64-t tiles ----------------
// 2 q-tiles per block — K/V staged once per 128 q-rows: halves staging, barriers,
// and K/V L2 traffic. Static-max softmax (p = exp(s-10), exact), cvt_pk bf16 pack,
// lane-local sum with one final reduce. 1D grid + XCD-chunk remap keeps all 5
// q-blocks of a (b,h) on one XCD.
__global__ __launch_bounds__(256) void attn_fused(
    const unsigned short* __restrict__ Q, const unsigned short* __restrict__ Kb,
    const unsigned short* __restrict__ Vt, unsigned short* __restrict__ Cc) {
  __shared__ __align__(16) unsigned short sK[64 * 72];     // +8 pad breaks 128B-stride conflicts
  __shared__ __align__(16) unsigned short sV[64 * 72];
  __shared__ __align__(16) unsigned short sP[4][16 * 72];
  const int tid  = threadIdx.x;
  const int wave = tid >> 6, lane = tid & 63;
  const int quad = lane >> 4, l15 = lane & 15;

  const int nb = gridDim.x;                 // 3840 = 768 bh * 5 q-pairs
  const int L = blockIdx.x;
  const int per = nb >> 3, rem = nb & 7;
  const int x8 = L & 7, i8 = L >> 3;
  const int g = x8 * per + (x8 < rem ? x8 : rem) + i8;
  const int bh = g / 5;
  const int qb = (g - bh * 5) * 128;

  int qr0 = qb + wave * 16 + l15; if (qr0 > SEQ - 1) qr0 = SEQ - 1;
  int qr1 = qr0 + 64; if (qr1 > SEQ - 1) qr1 = SEQ - 1;
  const unsigned short* q0p = Q + ((size_t)bh * SEQ + qr0) * HD;
  const unsigned short* q1p = Q + ((size_t)bh * SEQ + qr1) * HD;
  bf16x8 aQ[2][2];
  aQ[0][0] = *(const bf16x8*)(q0p + quad * 8);
  aQ[0][1] = *(const bf16x8*)(q0p + 32 + quad * 8);
  aQ[1][0] = *(const bf16x8*)(q1p + quad * 8);
  aQ[1][1] = *(const bf16x8*)(q1p + 32 + quad * 8);

  constexpr float L2E = 1.4426950408889634f;
  constexpr float OFF = 10.f * L2E;       // p = 2^(s*L2E - OFF) = exp(s-10)

  float l2[2][4] = {};
  f32x4 accO[2][4] = {};

  for (int t0 = 0; t0 < SEQ; t0 += 64) {
#pragma unroll
    for (int i = 0; i < 2; i++) {
      int c = tid + i * 256;                 // 0..511
      int row = c >> 3, col = (c & 7) << 3;
      int tk = t0 + row; if (tk > SEQ - 1) tk = SEQ - 1;
      bf16x8 vk = *(const bf16x8*)(Kb + ((size_t)bh * SEQ + tk) * HD + col);
      bf16x8 vv = *(const bf16x8*)(Vt + ((size_t)bh * HD + row) * VTS + t0 + col);
      *(bf16x8*)(sK + row * 72 + col) = vk;
      *(bf16x8*)(sV + row * 72 + col) = vv;
    }
    __syncthreads();

#pragma unroll
    for (int u = 0; u < 2; u++) {
      f32x4 s4[4];
#pragma unroll
      for (int ni = 0; ni < 4; ni++) {
        bf16x8 b0 = *(const bf16x8*)(sK + (ni * 16 + l15) * 72 + quad * 8);
        bf16x8 b1 = *(const bf16x8*)(sK + (ni * 16 + l15) * 72 + 32 + quad * 8);
        f32x4 a = {0.f, 0.f, 0.f, 0.f};
        a = mfma16(aQ[u][0], b0, a);
        a = mfma16(aQ[u][1], b1, a);
        s4[ni] = a;
      }
#pragma unroll
      for (int ni = 0; ni < 4; ni++) {
        if (t0 + ni * 16 + l15 >= SEQ) {
#pragma unroll
          for (int r = 0; r < 4; r++) s4[ni][r] = -3e38f;   // exp -> 0
        }
      }
#pragma unroll
      for (int r = 0; r < 4; r++) {
        float p0 = exp2f(fmaf(s4[0][r], L2E, -OFF));
        float p1 = exp2f(fmaf(s4[1][r], L2E, -OFF));
        float p2 = exp2f(fmaf(s4[2][r], L2E, -OFF));
        float p3 = exp2f(fmaf(s4[3][r], L2E, -OFF));
        l2[u][r] += (p0 + p1) + (p2 + p3);
        uint32_t pk01, pk23;
        asm("v_cvt_pk_bf16_f32 %0, %1, %2" : "=v"(pk01) : "v"(p0), "v"(p1));
        asm("v_cvt_pk_bf16_f32 %0, %1, %2" : "=v"(pk23) : "v"(p2), "v"(p3));
        unsigned short* prow = sP[wave] + (quad * 4 + r) * 72 + l15;
        prow[0]  = (unsigned short)pk01;
        prow[16] = (unsigned short)(pk01 >> 16);
        prow[32] = (unsigned short)pk23;
        prow[48] = (unsigned short)(pk23 >> 16);
      }
      bf16x8 aP0 = *(const bf16x8*)(sP[wave] + l15 * 72 + quad * 8);
      bf16x8 aP1 = *(const bf16x8*)(sP[wave] + l15 * 72 + 32 + quad * 8);
#pragma unroll
      for (int ni = 0; ni < 4; ni++) {
        bf16x8 v0 = *(const bf16x8*)(sV + (ni * 16 + l15) * 72 + quad * 8);
        bf16x8 v1 = *(const bf16x8*)(sV + (ni * 16 + l15) * 72 + 32 + quad * 8);
        accO[u][ni] = mfma16(aP0, v0, accO[u][ni]);
        accO[u][ni] = mfma16(aP1, v1, accO[u][ni]);
      }
    }
    __syncthreads();
  }

  // one final row-sum reduce (16-lane groups), then normalize+store
#pragma unroll
  for (int u = 0; u < 2; u++)
#pragma unroll
    for (int r = 0; r < 4; r++) {
#pragma unroll
      for (int o = 1; o < 16; o <<= 1) l2[u][r] += __shfl_xor(l2[u][r], o);
    }
  int bb = bh / NH, h = bh - bb * NH;
#pragma unroll
  for (int u = 0; u < 2; u++) {
#pragma unroll
    for (int r = 0; r < 4; r++) {
      int ss = qb + u * 64 + wave * 16 + quad * 4 + r;
      if (ss < SEQ) {
        float inv = __builtin_amdgcn_rcpf(l2[u][r]);
        size_t base = ((size_t)bb * SEQ + ss) * DM + h * HD;
#pragma unroll
        for (int ni = 0; ni < 4; ni++)
          Cc[base + ni * 16 + l15] = f2bf(accO[u][ni][r] * inv);
      }
    }
  }
}

// ---------------- host ----------------
extern "C" void kernel_launch(void* const* d_in, const int* in_sizes, int n_in,
                              void* d_out, int out_size, void* d_ws, size_t ws_size,
                              hipStream_t stream) {
  (void)in_sizes; (void)n_in; (void)out_size; (void)ws_size;
  const float* x     = (const float*)d_in[0];
  const float* ln1_g = (const float*)d_in[1];
  const float* ln1_b = (const float*)d_in[2];
  const float* Wq    = (const float*)d_in[3];
  const float* bq    = (const float*)d_in[4];
  const float* Wk    = (const float*)d_in[5];
  const float* bk    = (const float*)d_in[6];
  const float* Wv    = (const float*)d_in[7];
  const float* bv    = (const float*)d_in[8];
  const float* Wo    = (const float*)d_in[9];
  const float* bo    = (const float*)d_in[10];
  const float* ln2_g = (const float*)d_in[11];
  const float* ln2_b = (const float*)d_in[12];
  const float* W1    = (const float*)d_in[13];
  const float* b1    = (const float*)d_in[14];
  const float* W2    = (const float*)d_in[15];
  const float* b2    = (const float*)d_in[16];
  float* out = (float*)d_out;

  char* ws = (char*)d_ws;
  size_t off = 0;
  auto alloc = [&](size_t bytes) -> unsigned short* {
    unsigned short* p = (unsigned short*)(ws + off);
    off += (bytes + 255) & ~(size_t)255;
    return p;
  };
  unsigned short* h_bf  = alloc((size_t)ROWS * DM * 2);
  unsigned short* q_bf  = alloc((size_t)BHN * SEQ * HD * 2);
  unsigned short* k_bf  = alloc((size_t)BHN * SEQ * HD * 2);
  unsigned short* vt_bf = alloc((size_t)BHN * HD * VTS * 2);
  unsigned short* cc_bf = alloc((size_t)ROWS * DM * 2);
  // g_bf (226.9MB) aliases [q_bf ..) — q/k/vt/cc dead by then
  unsigned short* g_bf = q_bf;
  unsigned short* wqkv_t = alloc((size_t)2304 * 768 * 2);
  unsigned short* w1_t   = alloc((size_t)3072 * 768 * 2);
  unsigned short* w2_t   = alloc((size_t)768 * 3072 * 2);
  unsigned short* wo_t   = alloc((size_t)768 * 768 * 2);

  prep_qkv<<<(2304 * 768) / 256, 256, 0, stream>>>(Wq, Wk, Wv, wqkv_t);
  prep_t<<<(3072 * 768) / 256, 256, 0, stream>>>(W1, w1_t, 3072, 768);
  prep_t<<<(768 * 3072) / 256, 256, 0, stream>>>(W2, w2_t, 768, 3072);
  prep_t<<<(768 * 768) / 256, 256, 0, stream>>>(Wo, wo_t, 768, 768);

  const int MB = (ROWS + 127) / 128;   // 289 m-tiles

  ln_bf16<<<ROWS / 4, 256, 0, stream>>>(x, ln1_g, ln1_b, h_bf);
  gemm_bt<0><<<MB * 18, 256, 0, stream>>>(
      h_bf, wqkv_t, ROWS, 2304, 768, 18, bq, bk, bv, nullptr, nullptr, q_bf, k_bf, vt_bf);
  attn_fused<<<5 * BHN, 256, 0, stream>>>(q_bf, k_bf, vt_bf, cc_bf);
  gemm_bt<1><<<MB * 6, 256, 0, stream>>>(
      cc_bf, wo_t, ROWS, 768, 768, 6, bo, nullptr, nullptr, x, out, nullptr, nullptr, nullptr);
  ln_bf16<<<ROWS / 4, 256, 0, stream>>>(out, ln2_g, ln2_b, h_bf);
  gemm_bt<2><<<MB * 24, 256, 0, stream>>>(
      h_bf, w1_t, ROWS, 3072, 768, 24, b1, nullptr, nullptr, nullptr, nullptr, g_bf, nullptr, nullptr);
  gemm_bt<3><<<MB * 6, 256, 0, stream>>>(
      g_bf, w2_t, ROWS, 768, 3072, 6, b2, nullptr, nullptr, nullptr, out, nullptr, nullptr, nullptr);
}